// Round 18
// baseline (136.012 us; speedup 1.0000x reference)
//
#include <hip/hip_runtime.h>

#define N_NODES 50000
#define N_EDGES 800000

#define BVALS 64                                  // nodes per bucket
#define NBUK ((N_NODES + BVALS - 1) / BVALS)      // 782
#define PAD 16                                    // ints per padded counter (64B line)
#define CHUNK 4096                                // edges per count/scatter block
#define NSB ((N_EDGES + CHUNK - 1) / CHUNK)       // 196
#define BCAP 2048                                 // LDS capacity per bucket sort
#define PREPB 128                                 // prep_w blocks appended to count

typedef __attribute__((ext_vector_type(8))) short bf16x8;
typedef __attribute__((ext_vector_type(4))) float f32x4;

// ---------------- bf16 helpers ----------------

__device__ __forceinline__ float bf2f(unsigned short u) {
    return __uint_as_float(((unsigned)u) << 16);
}
__device__ __forceinline__ unsigned short f2bf(float f) {
    unsigned u = __float_as_uint(f);
    u += 0x7FFFu + ((u >> 16) & 1u);   // round-to-nearest-even
    return (unsigned short)(u >> 16);
}
__device__ __forceinline__ unsigned pack2bf(float a, float b) {
    return (unsigned)f2bf(a) | ((unsigned)f2bf(b) << 16);
}
__device__ __forceinline__ float lobf(int w) {
    return __uint_as_float(((unsigned)w) << 16);
}
__device__ __forceinline__ float hibf(int w) {
    return __uint_as_float(((unsigned)w) & 0xFFFF0000u);
}
__device__ __forceinline__ void stv(float* p, float v) { *p = v; }
__device__ __forceinline__ void stv(unsigned short* p, float v) { *p = f2bf(v); }

// accumulate 8 bf16 (int4) into float[8]
__device__ __forceinline__ void add8(float* a, int4 v) {
    a[0] += lobf(v.x); a[1] += hibf(v.x);
    a[2] += lobf(v.y); a[3] += hibf(v.y);
    a[4] += lobf(v.z); a[5] += hibf(v.z);
    a[6] += lobf(v.w); a[7] += hibf(v.w);
}

// ---------------- count (+fused weight prep) ----------------

__global__ __launch_bounds__(256) void count_prep_kernel(
        const int* __restrict__ ei, int* __restrict__ bhist,
        const float* __restrict__ W1l, const float* __restrict__ W1r,
        const float* __restrict__ W2l, const float* __restrict__ W2r,
        const float* __restrict__ Wm1,
        unsigned short* __restrict__ wt1, unsigned short* __restrict__ wt2,
        unsigned short* __restrict__ wtm, int E) {
    __shared__ int hist[NBUK];
    int t = threadIdx.x;
    if (blockIdx.x >= NSB) {
        int id = (blockIdx.x - NSB) * 256 + t;
        if (id < 128 * 128) {
            int k = id >> 7, c = id & 127;
            float v = (c < 64) ? W1l[k * 64 + c] : W1r[k * 64 + (c - 64)];
            wt1[c * 128 + k] = f2bf(v);
        } else if (id < 128 * 128 + 64 * 128) {
            int j = id - 128 * 128;
            int k = j >> 7, c = j & 127;
            float v = (c < 64) ? W2l[k * 64 + c] : W2r[k * 64 + (c - 64)];
            wt2[c * 64 + k] = f2bf(v);
        } else if (id < 128 * 128 + 64 * 128 + 64 * 128) {
            int j = id - 128 * 128 - 64 * 128;
            int k = j >> 7, c = j & 127;
            float v = (c < 64) ? Wm1[k * 64 + c] : Wm1[(64 + k) * 64 + (c - 64)];
            wtm[c * 64 + k] = f2bf(v);
        }
        return;
    }
    for (int h = t; h < NBUK; h += 256) hist[h] = 0;
    __syncthreads();
    int e0 = blockIdx.x * CHUNK;
    int ne = min(CHUNK, E - e0);
    for (int i = t; i < ne; i += 256)
        atomicAdd(&hist[ei[E + e0 + i] >> 6], 1);
    __syncthreads();
    for (int h = t; h < NBUK; h += 256)
        bhist[blockIdx.x * NBUK + h] = hist[h];
}

__global__ __launch_bounds__(1024) void scan_bcnt_kernel(
        const int* __restrict__ bhist, int* __restrict__ bofs,
        int* __restrict__ gcur_pad) {
    __shared__ int lds[1024];
    int t = threadIdx.x;
    int v = 0;
    if (t < NBUK)
        for (int b = 0; b < NSB; ++b) v += bhist[b * NBUK + t];
    lds[t] = v;
    __syncthreads();
    for (int off = 1; off < 1024; off <<= 1) {
        int u = (t >= off) ? lds[t - off] : 0;
        __syncthreads();
        lds[t] += u;
        __syncthreads();
    }
    if (t <= NBUK) bofs[t] = lds[t] - ((t < NBUK) ? v : 0);  // exclusive; bofs[NBUK]=E
    if (t < NBUK) gcur_pad[t * PAD] = lds[t] - v;            // scatter cursors
}

// ---------------- shared MFMA pieces ----------------
// fragment maps (guide sec.3, m89-verified):
//   A: row=lane&15, k=(lane>>4)*8+j ; B: col=lane&15, same k
//   D: col=lane&15, row=(lane>>4)*4+reg

template<int K>
__device__ __forceinline__ void stage_w(
        const unsigned short* __restrict__ WT, unsigned short* w_lds, int t) {
    constexpr int KP = K + 8;
    for (int idx = t; idx < 128 * K / 8; idx += 256) {
        int f = idx * 8;
        int r = f / K, c = f % K;
        *(int4*)&w_lds[r * KP + c] = *(const int4*)&WT[r * K + c];
    }
}

template<int K, typename T0, typename T1>
__device__ __forceinline__ void mfma_tile(
        const unsigned short* a_lds, const unsigned short* w_lds,
        int t, int n0, T0* __restrict__ C0, T1* __restrict__ C1, int N) {
    constexpr int KP = K + 8;
    int w = t >> 6, l = t & 63;
    int lr = l & 15;
    int lk = (l >> 4) * 8;

    f32x4 acc[8];
#pragma unroll
    for (int i = 0; i < 8; ++i) acc[i] = (f32x4)(0.f);

#pragma unroll
    for (int kc = 0; kc < K / 32; ++kc) {
        bf16x8 af = *(const bf16x8*)&a_lds[(w * 16 + lr) * KP + kc * 32 + lk];
#pragma unroll
        for (int ct = 0; ct < 8; ++ct) {
            bf16x8 bfr = *(const bf16x8*)&w_lds[(ct * 16 + lr) * KP + kc * 32 + lk];
            acc[ct] = __builtin_amdgcn_mfma_f32_16x16x32_bf16(af, bfr, acc[ct], 0, 0, 0);
        }
    }

    int orow = n0 + w * 16 + (l >> 4) * 4;
#pragma unroll
    for (int ct = 0; ct < 4; ++ct) {
#pragma unroll
        for (int r = 0; r < 4; ++r) {
            if (orow + r < N) stv(&C0[(size_t)(orow + r) * 64 + ct * 16 + lr], acc[ct][r]);
        }
    }
#pragma unroll
    for (int ct = 4; ct < 8; ++ct) {
#pragma unroll
        for (int r = 0; r < 4; ++r) {
            if (orow + r < N) stv(&C1[(size_t)(orow + r) * 64 + (ct - 4) * 16 + lr], acc[ct][r]);
        }
    }
}

// ---------------- merged: scatter (blocks 0..NSB) || gemm1 (rest) ----------
// scatter also records the original edge id alongside each packed entry.

__global__ __launch_bounds__(256) void scatter_gemm1_kernel(
        const int* __restrict__ ei, int* __restrict__ gcur_pad,
        unsigned int* __restrict__ bpk, int* __restrict__ bpk_id,
        const float* __restrict__ x, const unsigned short* __restrict__ wt1,
        unsigned short* __restrict__ C0, unsigned short* __restrict__ C1,
        int N, int E) {
    __shared__ __align__(16) char smem[52224];   // max(scatter 22.7KB, gemm 52224B)
    int t = threadIdx.x;

    if (blockIdx.x < NSB) {
        unsigned int* pk = (unsigned int*)smem;   // [CHUNK] 16KB
        int* hist  = (int*)(pk + CHUNK);          // [NBUK]
        int* lbase = hist + NBUK;                 // [NBUK]
        for (int h = t; h < NBUK; h += 256) hist[h] = 0;
        __syncthreads();
        int e0 = blockIdx.x * CHUNK;
        int ne = min(CHUNK, E - e0);
        for (int i = t; i < ne; i += 256) {
            unsigned s = (unsigned)ei[e0 + i];
            unsigned d = (unsigned)ei[E + e0 + i];
            pk[i] = (d << 16) | s;
            atomicAdd(&hist[d >> 6], 1);
        }
        __syncthreads();
        for (int h = t; h < NBUK; h += 256) {
            int c = hist[h];
            lbase[h] = c ? atomicAdd(&gcur_pad[h * PAD], c) : 0;
            hist[h] = 0;                     // reuse as local cursor
        }
        __syncthreads();
        for (int i = t; i < ne; i += 256) {
            unsigned v = pk[i];
            int h = (v >> 16) >> 6;
            int idx = atomicAdd(&hist[h], 1);
            bpk[lbase[h] + idx] = v;
            bpk_id[lbase[h] + idx] = e0 + i;
        }
        return;
    }

    // gemm1: K=128, A fp32 -> bf16 staging
    constexpr int K = 128, KP = K + 8;
    unsigned short* a_lds = (unsigned short*)smem;        // 64*136*2 = 17408
    unsigned short* w_lds = a_lds + 64 * KP;              // 128*136*2 = 34816
    int n0 = (blockIdx.x - NSB) * 64;

    for (int idx = t; idx < 64 * K / 4; idx += 256) {
        int f = idx * 4;
        int r = f / K, c = f % K;
        float4 v = make_float4(0.f, 0.f, 0.f, 0.f);
        if (n0 + r < N) v = *(const float4*)&x[(size_t)(n0 + r) * K + c];
        ushort4 o;
        o.x = f2bf(v.x); o.y = f2bf(v.y); o.z = f2bf(v.z); o.w = f2bf(v.w);
        *(ushort4*)&a_lds[r * KP + c] = o;
    }
    stage_w<K>(wt1, w_lds, t);
    __syncthreads();
    mfma_tile<K>(a_lds, w_lds, t, n0, C0, C1, N);
}

// ---------------- fused: bucket sort + agg1 + conv2 GEMM ----------------
// Block b sorts bucket b in LDS, writes packed elist ((dst<<16)|src) + eidx
// (original edge id) for later consumers, then aggregates xl[src] from the
// LDS-sorted list, forms h1 rows in a_lds, and runs the conv2 MFMA.

__global__ __launch_bounds__(256) void sort_agg_gemm_kernel(
        const unsigned int* __restrict__ bpk, const int* __restrict__ bpk_id,
        const int* __restrict__ bofs,
        int* __restrict__ rowptr, int* __restrict__ elist, int* __restrict__ eidx,
        const unsigned short* __restrict__ P, const unsigned short* __restrict__ R,
        const float* __restrict__ bias,
        const unsigned short* __restrict__ WT,
        unsigned short* __restrict__ C0, unsigned short* __restrict__ C1, int N) {
    constexpr int K = 64, KP = K + 8;
    __shared__ unsigned int pk[BCAP];            // 8KB
    __shared__ unsigned short srt[BCAP];         // 4KB sorted src
    __shared__ int sc[BVALS];
    __shared__ int ex[BVALS + 1];
    __shared__ int cur[BVALS];
    __shared__ unsigned short a_lds[64 * KP];    // 9216B
    __shared__ unsigned short w_lds[128 * KP];   // 18432B
    int t = threadIdx.x;
    int b = blockIdx.x;
    int n0 = b * 64;

    stage_w<K>(WT, w_lds, t);                    // independent of sort

    int e0 = bofs[b];
    int nb = min(bofs[b + 1] - e0, BCAP);

    if (t < BVALS) sc[t] = 0;
    __syncthreads();
    for (int i = t; i < nb; i += 256) {
        unsigned v = bpk[e0 + i];
        pk[i] = v;
        atomicAdd(&sc[(v >> 16) & 63], 1);
    }
    __syncthreads();
    int hv = (t < BVALS) ? sc[t] : 0;
#pragma unroll
    for (int off = 1; off < BVALS; off <<= 1) {
        int u = (t < BVALS && t >= off) ? sc[t - off] : 0;
        __syncthreads();
        if (t < BVALS) sc[t] += u;
        __syncthreads();
    }
    if (t < BVALS) {
        int e = sc[t] - hv;                      // exclusive prefix within bucket
        ex[t] = e;
        cur[t] = e;
        if (t == BVALS - 1) ex[BVALS] = nb;
        int n = n0 + t;
        if (n <= N_NODES) rowptr[n] = e0 + e;    // last bucket tail covers rowptr[N]=E
    }
    __syncthreads();
    for (int i = t; i < nb; i += 256) {
        unsigned v = pk[i];
        int pos = atomicAdd(&cur[(v >> 16) & 63], 1);
        srt[pos] = (unsigned short)(v & 0xFFFF);
        elist[e0 + pos] = (int)v;                // packed (dst<<16)|src
        eidx[e0 + pos] = bpk_id[e0 + i];         // original edge id
    }
    __syncthreads();

    // agg from LDS-sorted srt: 8 lanes/node, 2-way unrolled gather
    int l8 = t & 7;
    int nr = t >> 3;                              // 0..31
    float4 b0 = *(const float4*)&bias[l8 * 8];
    float4 b1 = *(const float4*)&bias[l8 * 8 + 4];

#pragma unroll
    for (int half = 0; half < 2; ++half) {
        int r = half * 32 + nr;
        int n = n0 + r;
        float a0[8] = {0.f, 0.f, 0.f, 0.f, 0.f, 0.f, 0.f, 0.f};
        float a1[8] = {0.f, 0.f, 0.f, 0.f, 0.f, 0.f, 0.f, 0.f};
        int rs = ex[r], re = ex[r + 1];
        int p = rs;
        for (; p + 2 <= re; p += 2) {
            int sA = srt[p], sB = srt[p + 1];
            int4 vA = *(const int4*)&P[(size_t)sA * 64 + l8 * 8];
            int4 vB = *(const int4*)&P[(size_t)sB * 64 + l8 * 8];
            add8(a0, vA);
            add8(a1, vB);
        }
        if (p < re) {
            int sA = srt[p];
            add8(a0, *(const int4*)&P[(size_t)sA * 64 + l8 * 8]);
        }
        int4 o = make_int4(0, 0, 0, 0);
        if (n < N) {
            float inv = 1.0f / fmaxf((float)(re - rs), 1.0f);
            int4 rv = *(const int4*)&R[(size_t)n * 64 + l8 * 8];
            float h0 = fmaxf(fmaf(a0[0] + a1[0], inv, b0.x + lobf(rv.x)), 0.f);
            float h1 = fmaxf(fmaf(a0[1] + a1[1], inv, b0.y + hibf(rv.x)), 0.f);
            float h2 = fmaxf(fmaf(a0[2] + a1[2], inv, b0.z + lobf(rv.y)), 0.f);
            float h3 = fmaxf(fmaf(a0[3] + a1[3], inv, b0.w + hibf(rv.y)), 0.f);
            float h4 = fmaxf(fmaf(a0[4] + a1[4], inv, b1.x + lobf(rv.z)), 0.f);
            float h5 = fmaxf(fmaf(a0[5] + a1[5], inv, b1.y + hibf(rv.z)), 0.f);
            float h6 = fmaxf(fmaf(a0[6] + a1[6], inv, b1.z + lobf(rv.w)), 0.f);
            float h7 = fmaxf(fmaf(a0[7] + a1[7], inv, b1.w + hibf(rv.w)), 0.f);
            o.x = pack2bf(h0, h1); o.y = pack2bf(h2, h3);
            o.z = pack2bf(h4, h5); o.w = pack2bf(h6, h7);
        }
        *(int4*)&a_lds[r * KP + l8 * 8] = o;
    }
    __syncthreads();
    mfma_tile<K>(a_lds, w_lds, t, n0, C0, C1, N);
}

// ---------------- fused agg + gemm (agg2; reads global rowptr + packed elist) ----

__global__ __launch_bounds__(256) void agg_gemm_kernel(
        const unsigned short* __restrict__ P, const unsigned short* __restrict__ R,
        const float* __restrict__ bias,
        const int* __restrict__ rowptr, const int* __restrict__ elist,
        const unsigned short* __restrict__ WT,
        unsigned short* __restrict__ C0, unsigned short* __restrict__ C1, int N) {
    constexpr int K = 64, KP = K + 8;
    __shared__ unsigned short a_lds[64 * KP];    // 9216B
    __shared__ unsigned short w_lds[128 * KP];   // 18432B
    int t = threadIdx.x;
    int n0 = blockIdx.x * 64;

    stage_w<K>(WT, w_lds, t);

    int l8 = t & 7;
    int nr = t >> 3;                              // 0..31
    float4 b0 = *(const float4*)&bias[l8 * 8];
    float4 b1 = *(const float4*)&bias[l8 * 8 + 4];

#pragma unroll
    for (int half = 0; half < 2; ++half) {
        int r = half * 32 + nr;
        int n = n0 + r;
        float a0[8] = {0.f, 0.f, 0.f, 0.f, 0.f, 0.f, 0.f, 0.f};
        float a1[8] = {0.f, 0.f, 0.f, 0.f, 0.f, 0.f, 0.f, 0.f};
        int r0 = 0, r1 = 0;
        if (n < N) { r0 = rowptr[n]; r1 = rowptr[n + 1]; }
        int p = r0;
        for (; p + 2 <= r1; p += 2) {
            int sA = elist[p] & 0xFFFF, sB = elist[p + 1] & 0xFFFF;
            int4 vA = *(const int4*)&P[(size_t)sA * 64 + l8 * 8];
            int4 vB = *(const int4*)&P[(size_t)sB * 64 + l8 * 8];
            add8(a0, vA);
            add8(a1, vB);
        }
        if (p < r1) {
            int sA = elist[p] & 0xFFFF;
            add8(a0, *(const int4*)&P[(size_t)sA * 64 + l8 * 8]);
        }
        int4 o = make_int4(0, 0, 0, 0);
        if (n < N) {
            float inv = 1.0f / fmaxf((float)(r1 - r0), 1.0f);
            int4 rv = *(const int4*)&R[(size_t)n * 64 + l8 * 8];
            float h0 = fmaxf(fmaf(a0[0] + a1[0], inv, b0.x + lobf(rv.x)), 0.f);
            float h1 = fmaxf(fmaf(a0[1] + a1[1], inv, b0.y + hibf(rv.x)), 0.f);
            float h2 = fmaxf(fmaf(a0[2] + a1[2], inv, b0.z + lobf(rv.y)), 0.f);
            float h3 = fmaxf(fmaf(a0[3] + a1[3], inv, b0.w + hibf(rv.y)), 0.f);
            float h4 = fmaxf(fmaf(a0[4] + a1[4], inv, b1.x + lobf(rv.z)), 0.f);
            float h5 = fmaxf(fmaf(a0[5] + a1[5], inv, b1.y + hibf(rv.z)), 0.f);
            float h6 = fmaxf(fmaf(a0[6] + a1[6], inv, b1.z + lobf(rv.w)), 0.f);
            float h7 = fmaxf(fmaf(a0[7] + a1[7], inv, b1.w + hibf(rv.w)), 0.f);
            o.x = pack2bf(h0, h1); o.y = pack2bf(h2, h3);
            o.z = pack2bf(h4, h5); o.w = pack2bf(h6, h7);
        }
        *(int4*)&a_lds[r * KP + l8 * 8] = o;
    }
    __syncthreads();
    mfma_tile<K>(a_lds, w_lds, t, n0, C0, C1, N);
}

// ---------------- edge output (dst-sorted order, uniform 8 lanes/edge) ----------
// p = sorted position; v = elist[p] = (dst<<16)|src; out[eidx[p]] = result.
// Consecutive sorted edges share dst -> Pb row loads collapse to L1 hits.

__global__ __launch_bounds__(256) void edge_out_kernel(
        const unsigned short* __restrict__ Pa, const unsigned short* __restrict__ Pb,
        const int* __restrict__ elist, const int* __restrict__ eidx,
        const float* __restrict__ bm1,
        const float* __restrict__ Wm2, const float* __restrict__ bm2,
        float* __restrict__ out, int E) {
    int t = threadIdx.x;
    int l8 = t & 7;
    int eg = t >> 3;                       // 0..31
    int base = blockIdx.x * 128 + eg;

    float4 wA = *(const float4*)&Wm2[l8 * 16];       // rows l8*8+0,1 (2 cols each)
    float4 wB = *(const float4*)&Wm2[l8 * 16 + 4];   // rows +2,3
    float4 wC = *(const float4*)&Wm2[l8 * 16 + 8];   // rows +4,5
    float4 wD = *(const float4*)&Wm2[l8 * 16 + 12];  // rows +6,7
    float4 bbA = *(const float4*)&bm1[l8 * 8];
    float4 bbB = *(const float4*)&bm1[l8 * 8 + 4];
    float ob0 = bm2[0], ob1 = bm2[1];

#pragma unroll
    for (int it = 0; it < 4; ++it) {
        int p = base + it * 32;
        int v = elist[p];
        int oid = eidx[p];
        int s = v & 0xFFFF;
        int d = ((unsigned)v) >> 16;
        int4 ua = *(const int4*)&Pa[(size_t)s * 64 + l8 * 8];
        int4 ub = *(const int4*)&Pb[(size_t)d * 64 + l8 * 8];
        float h0 = fmaxf(lobf(ua.x) + lobf(ub.x) + bbA.x, 0.f);
        float h1 = fmaxf(hibf(ua.x) + hibf(ub.x) + bbA.y, 0.f);
        float h2 = fmaxf(lobf(ua.y) + lobf(ub.y) + bbA.z, 0.f);
        float h3 = fmaxf(hibf(ua.y) + hibf(ub.y) + bbA.w, 0.f);
        float h4 = fmaxf(lobf(ua.z) + lobf(ub.z) + bbB.x, 0.f);
        float h5 = fmaxf(hibf(ua.z) + hibf(ub.z) + bbB.y, 0.f);
        float h6 = fmaxf(lobf(ua.w) + lobf(ub.w) + bbB.z, 0.f);
        float h7 = fmaxf(hibf(ua.w) + hibf(ub.w) + bbB.w, 0.f);
        float s0 = h0 * wA.x + h1 * wA.z + h2 * wB.x + h3 * wB.z
                 + h4 * wC.x + h5 * wC.z + h6 * wD.x + h7 * wD.z;
        float s1 = h0 * wA.y + h1 * wA.w + h2 * wB.y + h3 * wB.w
                 + h4 * wC.y + h5 * wC.w + h6 * wD.y + h7 * wD.w;
#pragma unroll
        for (int off = 4; off >= 1; off >>= 1) {
            s0 += __shfl_xor(s0, off, 64);
            s1 += __shfl_xor(s1, off, 64);
        }
        if (l8 == 0) {
            *(float2*)&out[(size_t)oid * 2] = make_float2(s0 + ob0, s1 + ob1);
        }
    }
}

// ---------------- launch ----------------

extern "C" void kernel_launch(void* const* d_in, const int* in_sizes, int n_in,
                              void* d_out, int out_size, void* d_ws, size_t ws_size,
                              hipStream_t stream) {
    const float* x   = (const float*)d_in[0];
    const int*   ei  = (const int*)d_in[1];
    const float* W1l = (const float*)d_in[2];
    const float* b1l = (const float*)d_in[3];
    const float* W1r = (const float*)d_in[4];
    const float* W2l = (const float*)d_in[5];
    const float* b2l = (const float*)d_in[6];
    const float* W2r = (const float*)d_in[7];
    const float* Wm1 = (const float*)d_in[8];
    const float* bm1 = (const float*)d_in[9];
    const float* Wm2 = (const float*)d_in[10];
    const float* bm2 = (const float*)d_in[11];
    float* out = (float*)d_out;

    const int N = N_NODES, E = N_EDGES;

    // slots (all tables bf16):
    //   B0h: xl (gemm1) -> Pa (fused2)
    //   B1h: p1r (gemm1) -> p2r (fused1, same rows) [residual]
    //   B2 : bpk + bpk_id (CSR build, 6.4MB total; dead after fused sort)
    //   B3h: Pb (fused2)
    //   B4h: p2l (fused1)  [fresh slot -- fixes round-17 latent race vs bpk]
    float* B0 = (float*)d_ws;
    float* B1 = B0 + (size_t)N * 64;
    float* B2 = B1 + (size_t)N * 64;
    unsigned short* B3h = (unsigned short*)(B2 + (size_t)N * 64);   // [N*64] 6.4MB
    unsigned short* B4h = B3h + (size_t)N * 64;                     // [N*64] 6.4MB
    int* rowptr   = (int*)(B4h + (size_t)N * 64);    // [N+1]
    int* elist    = rowptr + N + 1;                  // [E] packed (dst<<16)|src
    int* eidx     = elist + E;                       // [E] original edge ids
    int* bofs     = eidx + E;                        // [NBUK+1]
    int* gcur_pad = bofs + NBUK + 1;                 // [NBUK*PAD] 50KB
    int* bhist    = gcur_pad + NBUK * PAD;           // [NSB*NBUK] 613KB
    unsigned short* wt1 = (unsigned short*)(bhist + NSB * NBUK);  // [128*128] 32KB
    unsigned short* wt2 = wt1 + 128 * 128;                        // [128*64] 16KB
    unsigned short* wtm = wt2 + 128 * 64;                         // [128*64] 16KB
    unsigned int* bpk = (unsigned int*)B2;           // [E] 3.2 MB
    int* bpk_id = (int*)(bpk + E);                   // [E] 3.2 MB

    unsigned short* B0h = (unsigned short*)B0;
    unsigned short* B1h = (unsigned short*)B1;

    // CSR build (+fused weight prep): count -> scan
    count_prep_kernel<<<NSB + PREPB, 256, 0, stream>>>(
        ei, bhist, W1l, W1r, W2l, W2r, Wm1, wt1, wt2, wtm, E);
    scan_bcnt_kernel<<<1, 1024, 0, stream>>>(bhist, bofs, gcur_pad);

    // bucket scatter || conv1 GEMM: xl = x@W1l (B0h), p1r = x@W1r (B1h)
    scatter_gemm1_kernel<<<NSB + (N + 63) / 64, 256, 0, stream>>>(
        ei, gcur_pad, bpk, bpk_id, x, wt1, B0h, B1h, N, E);

    // fused sort + agg1 + conv2 GEMM: sort bucket -> rowptr/elist/eidx;
    //   h1 = relu(mean xl[src] + b1l + p1r) -> LDS;
    //   p2l = h1@W2l (B4h), p2r = h1@W2r (B1h, same rows as p1r)
    sort_agg_gemm_kernel<<<NBUK, 256, 0, stream>>>(
        bpk, bpk_id, bofs, rowptr, elist, eidx, B0h, B1h, b1l, wt2, B4h, B1h, N);

    // fused agg2 + edge-MLP GEMM: h2 = relu(mean p2l[src] + b2l + p2r) -> LDS;
    //   Pa = h2@Wm1_top (B0h), Pb = h2@Wm1_bot (B3h)
    agg_gemm_kernel<<<(N + 63) / 64, 256, 0, stream>>>(
        B4h, B1h, b2l, rowptr, elist, wtm, B0h, B3h, N);

    // per-edge (dst-sorted): out[eidx[p]] = relu(Pa[src] + Pb[dst] + bm1) @ Wm2 + bm2
    edge_out_kernel<<<E / 128, 256, 0, stream>>>(
        B0h, B3h, elist, eidx, bm1, Wm2, bm2, out, E);
}

// Round 19
// 123.687 us; speedup vs baseline: 1.0997x; 1.0997x over previous
//
#include <hip/hip_runtime.h>

#define N_NODES 50000
#define N_EDGES 800000

#define BVALS 64                                  // nodes per bucket
#define NBUK ((N_NODES + BVALS - 1) / BVALS)      // 782
#define PAD 16                                    // ints per padded counter (64B line)
#define CHUNK 4096                                // edges per count/scatter block
#define NSB ((N_EDGES + CHUNK - 1) / CHUNK)       // 196
#define BCAP 2048                                 // LDS capacity per bucket sort
#define PREPB 128                                 // prep_w blocks appended to count

typedef __attribute__((ext_vector_type(8))) short bf16x8;
typedef __attribute__((ext_vector_type(4))) float f32x4;

// ---------------- bf16 helpers ----------------

__device__ __forceinline__ float bf2f(unsigned short u) {
    return __uint_as_float(((unsigned)u) << 16);
}
__device__ __forceinline__ unsigned short f2bf(float f) {
    unsigned u = __float_as_uint(f);
    u += 0x7FFFu + ((u >> 16) & 1u);   // round-to-nearest-even
    return (unsigned short)(u >> 16);
}
__device__ __forceinline__ unsigned pack2bf(float a, float b) {
    return (unsigned)f2bf(a) | ((unsigned)f2bf(b) << 16);
}
__device__ __forceinline__ float lobf(int w) {
    return __uint_as_float(((unsigned)w) << 16);
}
__device__ __forceinline__ float hibf(int w) {
    return __uint_as_float(((unsigned)w) & 0xFFFF0000u);
}
__device__ __forceinline__ void stv(float* p, float v) { *p = v; }
__device__ __forceinline__ void stv(unsigned short* p, float v) { *p = f2bf(v); }

// accumulate 8 bf16 (int4) into float[8]
__device__ __forceinline__ void add8(float* a, int4 v) {
    a[0] += lobf(v.x); a[1] += hibf(v.x);
    a[2] += lobf(v.y); a[3] += hibf(v.y);
    a[4] += lobf(v.z); a[5] += hibf(v.z);
    a[6] += lobf(v.w); a[7] += hibf(v.w);
}

// ---------------- count (+fused weight prep) ----------------

__global__ __launch_bounds__(256) void count_prep_kernel(
        const int* __restrict__ ei, int* __restrict__ bhist,
        const float* __restrict__ W1l, const float* __restrict__ W1r,
        const float* __restrict__ W2l, const float* __restrict__ W2r,
        const float* __restrict__ Wm1,
        unsigned short* __restrict__ wt1, unsigned short* __restrict__ wt2,
        unsigned short* __restrict__ wtm, int E) {
    __shared__ int hist[NBUK];
    int t = threadIdx.x;
    if (blockIdx.x >= NSB) {
        int id = (blockIdx.x - NSB) * 256 + t;
        if (id < 128 * 128) {
            int k = id >> 7, c = id & 127;
            float v = (c < 64) ? W1l[k * 64 + c] : W1r[k * 64 + (c - 64)];
            wt1[c * 128 + k] = f2bf(v);
        } else if (id < 128 * 128 + 64 * 128) {
            int j = id - 128 * 128;
            int k = j >> 7, c = j & 127;
            float v = (c < 64) ? W2l[k * 64 + c] : W2r[k * 64 + (c - 64)];
            wt2[c * 64 + k] = f2bf(v);
        } else if (id < 128 * 128 + 64 * 128 + 64 * 128) {
            int j = id - 128 * 128 - 64 * 128;
            int k = j >> 7, c = j & 127;
            float v = (c < 64) ? Wm1[k * 64 + c] : Wm1[(64 + k) * 64 + (c - 64)];
            wtm[c * 64 + k] = f2bf(v);
        }
        return;
    }
    for (int h = t; h < NBUK; h += 256) hist[h] = 0;
    __syncthreads();
    int e0 = blockIdx.x * CHUNK;
    int ne = min(CHUNK, E - e0);
    for (int i = t; i < ne; i += 256)
        atomicAdd(&hist[ei[E + e0 + i] >> 6], 1);
    __syncthreads();
    for (int h = t; h < NBUK; h += 256)
        bhist[blockIdx.x * NBUK + h] = hist[h];
}

__global__ __launch_bounds__(1024) void scan_bcnt_kernel(
        const int* __restrict__ bhist, int* __restrict__ bofs,
        int* __restrict__ gcur_pad) {
    __shared__ int lds[1024];
    int t = threadIdx.x;
    int v = 0;
    if (t < NBUK)
        for (int b = 0; b < NSB; ++b) v += bhist[b * NBUK + t];
    lds[t] = v;
    __syncthreads();
    for (int off = 1; off < 1024; off <<= 1) {
        int u = (t >= off) ? lds[t - off] : 0;
        __syncthreads();
        lds[t] += u;
        __syncthreads();
    }
    if (t <= NBUK) bofs[t] = lds[t] - ((t < NBUK) ? v : 0);  // exclusive; bofs[NBUK]=E
    if (t < NBUK) gcur_pad[t * PAD] = lds[t] - v;            // scatter cursors
}

// ---------------- shared MFMA pieces ----------------
// fragment maps (guide sec.3, m89-verified):
//   A: row=lane&15, k=(lane>>4)*8+j ; B: col=lane&15, same k
//   D: col=lane&15, row=(lane>>4)*4+reg

template<int K>
__device__ __forceinline__ void stage_w(
        const unsigned short* __restrict__ WT, unsigned short* w_lds, int t) {
    constexpr int KP = K + 8;
    for (int idx = t; idx < 128 * K / 8; idx += 256) {
        int f = idx * 8;
        int r = f / K, c = f % K;
        *(int4*)&w_lds[r * KP + c] = *(const int4*)&WT[r * K + c];
    }
}

template<int K, typename T0, typename T1>
__device__ __forceinline__ void mfma_tile(
        const unsigned short* a_lds, const unsigned short* w_lds,
        int t, int n0, T0* __restrict__ C0, T1* __restrict__ C1, int N) {
    constexpr int KP = K + 8;
    int w = t >> 6, l = t & 63;
    int lr = l & 15;
    int lk = (l >> 4) * 8;

    f32x4 acc[8];
#pragma unroll
    for (int i = 0; i < 8; ++i) acc[i] = (f32x4)(0.f);

#pragma unroll
    for (int kc = 0; kc < K / 32; ++kc) {
        bf16x8 af = *(const bf16x8*)&a_lds[(w * 16 + lr) * KP + kc * 32 + lk];
#pragma unroll
        for (int ct = 0; ct < 8; ++ct) {
            bf16x8 bfr = *(const bf16x8*)&w_lds[(ct * 16 + lr) * KP + kc * 32 + lk];
            acc[ct] = __builtin_amdgcn_mfma_f32_16x16x32_bf16(af, bfr, acc[ct], 0, 0, 0);
        }
    }

    int orow = n0 + w * 16 + (l >> 4) * 4;
#pragma unroll
    for (int ct = 0; ct < 4; ++ct) {
#pragma unroll
        for (int r = 0; r < 4; ++r) {
            if (orow + r < N) stv(&C0[(size_t)(orow + r) * 64 + ct * 16 + lr], acc[ct][r]);
        }
    }
#pragma unroll
    for (int ct = 4; ct < 8; ++ct) {
#pragma unroll
        for (int r = 0; r < 4; ++r) {
            if (orow + r < N) stv(&C1[(size_t)(orow + r) * 64 + (ct - 4) * 16 + lr], acc[ct][r]);
        }
    }
}

// ---------------- merged: scatter (blocks 0..NSB) || gemm1 (rest) ----------
// Both depend only on {scan outputs} / {wt1, x} -- independent of each other.

__global__ __launch_bounds__(256) void scatter_gemm1_kernel(
        const int* __restrict__ ei, int* __restrict__ gcur_pad,
        unsigned int* __restrict__ bpk,
        const float* __restrict__ x, const unsigned short* __restrict__ wt1,
        unsigned short* __restrict__ C0, unsigned short* __restrict__ C1,
        int N, int E) {
    __shared__ __align__(16) char smem[52224];   // max(scatter 22.7KB, gemm 52224B)
    int t = threadIdx.x;

    if (blockIdx.x < NSB) {
        unsigned int* pk = (unsigned int*)smem;   // [CHUNK] 16KB
        int* hist  = (int*)(pk + CHUNK);          // [NBUK]
        int* lbase = hist + NBUK;                 // [NBUK]
        for (int h = t; h < NBUK; h += 256) hist[h] = 0;
        __syncthreads();
        int e0 = blockIdx.x * CHUNK;
        int ne = min(CHUNK, E - e0);
        for (int i = t; i < ne; i += 256) {
            unsigned s = (unsigned)ei[e0 + i];
            unsigned d = (unsigned)ei[E + e0 + i];
            pk[i] = (d << 16) | s;
            atomicAdd(&hist[d >> 6], 1);
        }
        __syncthreads();
        for (int h = t; h < NBUK; h += 256) {
            int c = hist[h];
            lbase[h] = c ? atomicAdd(&gcur_pad[h * PAD], c) : 0;
            hist[h] = 0;                     // reuse as local cursor
        }
        __syncthreads();
        for (int i = t; i < ne; i += 256) {
            unsigned v = pk[i];
            int h = (v >> 16) >> 6;
            int idx = atomicAdd(&hist[h], 1);
            bpk[lbase[h] + idx] = v;
        }
        return;
    }

    // gemm1: K=128, A fp32 -> bf16 staging
    constexpr int K = 128, KP = K + 8;
    unsigned short* a_lds = (unsigned short*)smem;        // 64*136*2 = 17408
    unsigned short* w_lds = a_lds + 64 * KP;              // 128*136*2 = 34816
    int n0 = (blockIdx.x - NSB) * 64;

    for (int idx = t; idx < 64 * K / 4; idx += 256) {
        int f = idx * 4;
        int r = f / K, c = f % K;
        float4 v = make_float4(0.f, 0.f, 0.f, 0.f);
        if (n0 + r < N) v = *(const float4*)&x[(size_t)(n0 + r) * K + c];
        ushort4 o;
        o.x = f2bf(v.x); o.y = f2bf(v.y); o.z = f2bf(v.z); o.w = f2bf(v.w);
        *(ushort4*)&a_lds[r * KP + c] = o;
    }
    stage_w<K>(wt1, w_lds, t);
    __syncthreads();
    mfma_tile<K>(a_lds, w_lds, t, n0, C0, C1, N);
}

// ---------------- fused: bucket sort + agg1 + conv2 GEMM ----------------
// Block b sorts bucket b (64 dst nodes) in LDS, writes rowptr/elist (for agg2),
// then aggregates xl[src] from the LDS-sorted list, forms h1 rows in a_lds,
// and runs the conv2 MFMA. No global elist/rowptr round-trip for agg1.

__global__ __launch_bounds__(256) void sort_agg_gemm_kernel(
        const unsigned int* __restrict__ bpk, const int* __restrict__ bofs,
        int* __restrict__ rowptr, int* __restrict__ elist,
        const unsigned short* __restrict__ P, const unsigned short* __restrict__ R,
        const float* __restrict__ bias,
        const unsigned short* __restrict__ WT,
        unsigned short* __restrict__ C0, unsigned short* __restrict__ C1, int N) {
    constexpr int K = 64, KP = K + 8;
    __shared__ unsigned int pk[BCAP];            // 8KB
    __shared__ unsigned short srt[BCAP];         // 4KB sorted src
    __shared__ int sc[BVALS];
    __shared__ int ex[BVALS + 1];
    __shared__ int cur[BVALS];
    __shared__ unsigned short a_lds[64 * KP];    // 9216B
    __shared__ unsigned short w_lds[128 * KP];   // 18432B
    int t = threadIdx.x;
    int b = blockIdx.x;
    int n0 = b * 64;

    stage_w<K>(WT, w_lds, t);                    // independent of sort

    int e0 = bofs[b];
    int nb = min(bofs[b + 1] - e0, BCAP);

    if (t < BVALS) sc[t] = 0;
    __syncthreads();
    for (int i = t; i < nb; i += 256) {
        unsigned v = bpk[e0 + i];
        pk[i] = v;
        atomicAdd(&sc[(v >> 16) & 63], 1);
    }
    __syncthreads();
    int hv = (t < BVALS) ? sc[t] : 0;
#pragma unroll
    for (int off = 1; off < BVALS; off <<= 1) {
        int u = (t < BVALS && t >= off) ? sc[t - off] : 0;
        __syncthreads();
        if (t < BVALS) sc[t] += u;
        __syncthreads();
    }
    if (t < BVALS) {
        int e = sc[t] - hv;                      // exclusive prefix within bucket
        ex[t] = e;
        cur[t] = e;
        if (t == BVALS - 1) ex[BVALS] = nb;
        int n = n0 + t;
        if (n <= N_NODES) rowptr[n] = e0 + e;    // last bucket tail covers rowptr[N]=E
    }
    __syncthreads();
    for (int i = t; i < nb; i += 256) {
        unsigned v = pk[i];
        int pos = atomicAdd(&cur[(v >> 16) & 63], 1);
        srt[pos] = (unsigned short)(v & 0xFFFF);
        elist[e0 + pos] = (int)(v & 0xFFFF);     // for agg2
    }
    __syncthreads();

    // agg from LDS-sorted srt: 8 lanes/node, 2-way unrolled gather
    int l8 = t & 7;
    int nr = t >> 3;                              // 0..31
    float4 b0 = *(const float4*)&bias[l8 * 8];
    float4 b1 = *(const float4*)&bias[l8 * 8 + 4];

#pragma unroll
    for (int half = 0; half < 2; ++half) {
        int r = half * 32 + nr;
        int n = n0 + r;
        float a0[8] = {0.f, 0.f, 0.f, 0.f, 0.f, 0.f, 0.f, 0.f};
        float a1[8] = {0.f, 0.f, 0.f, 0.f, 0.f, 0.f, 0.f, 0.f};
        int rs = ex[r], re = ex[r + 1];
        int p = rs;
        for (; p + 2 <= re; p += 2) {
            int sA = srt[p], sB = srt[p + 1];
            int4 vA = *(const int4*)&P[(size_t)sA * 64 + l8 * 8];
            int4 vB = *(const int4*)&P[(size_t)sB * 64 + l8 * 8];
            add8(a0, vA);
            add8(a1, vB);
        }
        if (p < re) {
            int sA = srt[p];
            add8(a0, *(const int4*)&P[(size_t)sA * 64 + l8 * 8]);
        }
        int4 o = make_int4(0, 0, 0, 0);
        if (n < N) {
            float inv = 1.0f / fmaxf((float)(re - rs), 1.0f);
            int4 rv = *(const int4*)&R[(size_t)n * 64 + l8 * 8];
            float h0 = fmaxf(fmaf(a0[0] + a1[0], inv, b0.x + lobf(rv.x)), 0.f);
            float h1 = fmaxf(fmaf(a0[1] + a1[1], inv, b0.y + hibf(rv.x)), 0.f);
            float h2 = fmaxf(fmaf(a0[2] + a1[2], inv, b0.z + lobf(rv.y)), 0.f);
            float h3 = fmaxf(fmaf(a0[3] + a1[3], inv, b0.w + hibf(rv.y)), 0.f);
            float h4 = fmaxf(fmaf(a0[4] + a1[4], inv, b1.x + lobf(rv.z)), 0.f);
            float h5 = fmaxf(fmaf(a0[5] + a1[5], inv, b1.y + hibf(rv.z)), 0.f);
            float h6 = fmaxf(fmaf(a0[6] + a1[6], inv, b1.z + lobf(rv.w)), 0.f);
            float h7 = fmaxf(fmaf(a0[7] + a1[7], inv, b1.w + hibf(rv.w)), 0.f);
            o.x = pack2bf(h0, h1); o.y = pack2bf(h2, h3);
            o.z = pack2bf(h4, h5); o.w = pack2bf(h6, h7);
        }
        *(int4*)&a_lds[r * KP + l8 * 8] = o;
    }
    __syncthreads();
    mfma_tile<K>(a_lds, w_lds, t, n0, C0, C1, N);
}

// ---------------- fused agg + gemm (agg2; reads global rowptr/elist) ----------

__global__ __launch_bounds__(256) void agg_gemm_kernel(
        const unsigned short* __restrict__ P, const unsigned short* __restrict__ R,
        const float* __restrict__ bias,
        const int* __restrict__ rowptr, const int* __restrict__ elist,
        const unsigned short* __restrict__ WT,
        unsigned short* __restrict__ C0, unsigned short* __restrict__ C1, int N) {
    constexpr int K = 64, KP = K + 8;
    __shared__ unsigned short a_lds[64 * KP];    // 9216B
    __shared__ unsigned short w_lds[128 * KP];   // 18432B
    int t = threadIdx.x;
    int n0 = blockIdx.x * 64;

    stage_w<K>(WT, w_lds, t);

    int l8 = t & 7;
    int nr = t >> 3;                              // 0..31
    float4 b0 = *(const float4*)&bias[l8 * 8];
    float4 b1 = *(const float4*)&bias[l8 * 8 + 4];

#pragma unroll
    for (int half = 0; half < 2; ++half) {
        int r = half * 32 + nr;
        int n = n0 + r;
        float a0[8] = {0.f, 0.f, 0.f, 0.f, 0.f, 0.f, 0.f, 0.f};
        float a1[8] = {0.f, 0.f, 0.f, 0.f, 0.f, 0.f, 0.f, 0.f};
        int r0 = 0, r1 = 0;
        if (n < N) { r0 = rowptr[n]; r1 = rowptr[n + 1]; }
        int p = r0;
        for (; p + 2 <= r1; p += 2) {
            int sA = elist[p], sB = elist[p + 1];
            int4 vA = *(const int4*)&P[(size_t)sA * 64 + l8 * 8];
            int4 vB = *(const int4*)&P[(size_t)sB * 64 + l8 * 8];
            add8(a0, vA);
            add8(a1, vB);
        }
        if (p < r1) {
            int sA = elist[p];
            add8(a0, *(const int4*)&P[(size_t)sA * 64 + l8 * 8]);
        }
        int4 o = make_int4(0, 0, 0, 0);
        if (n < N) {
            float inv = 1.0f / fmaxf((float)(r1 - r0), 1.0f);
            int4 rv = *(const int4*)&R[(size_t)n * 64 + l8 * 8];
            float h0 = fmaxf(fmaf(a0[0] + a1[0], inv, b0.x + lobf(rv.x)), 0.f);
            float h1 = fmaxf(fmaf(a0[1] + a1[1], inv, b0.y + hibf(rv.x)), 0.f);
            float h2 = fmaxf(fmaf(a0[2] + a1[2], inv, b0.z + lobf(rv.y)), 0.f);
            float h3 = fmaxf(fmaf(a0[3] + a1[3], inv, b0.w + hibf(rv.y)), 0.f);
            float h4 = fmaxf(fmaf(a0[4] + a1[4], inv, b1.x + lobf(rv.z)), 0.f);
            float h5 = fmaxf(fmaf(a0[5] + a1[5], inv, b1.y + hibf(rv.z)), 0.f);
            float h6 = fmaxf(fmaf(a0[6] + a1[6], inv, b1.z + lobf(rv.w)), 0.f);
            float h7 = fmaxf(fmaf(a0[7] + a1[7], inv, b1.w + hibf(rv.w)), 0.f);
            o.x = pack2bf(h0, h1); o.y = pack2bf(h2, h3);
            o.z = pack2bf(h4, h5); o.w = pack2bf(h6, h7);
        }
        *(int4*)&a_lds[r * KP + l8 * 8] = o;
    }
    __syncthreads();
    mfma_tile<K>(a_lds, w_lds, t, n0, C0, C1, N);
}

// ---------------- edge output: out[e] = relu(Pa[src] + Pb[dst] + bm1) @ Wm2 + bm2 ----
// 8 lanes/edge (int4 = 16B of the 128B row), 32 edges/wave-pass, 128 edges/block.

__global__ __launch_bounds__(256) void edge_out_kernel(
        const unsigned short* __restrict__ Pa, const unsigned short* __restrict__ Pb,
        const int* __restrict__ ei,
        const float* __restrict__ bm1,
        const float* __restrict__ Wm2, const float* __restrict__ bm2,
        float* __restrict__ out, int E) {
    int t = threadIdx.x;
    int l8 = t & 7;
    int eg = t >> 3;                       // 0..31
    int base = blockIdx.x * 128 + eg;

    float4 wA = *(const float4*)&Wm2[l8 * 16];       // rows l8*8+0,1 (2 cols each)
    float4 wB = *(const float4*)&Wm2[l8 * 16 + 4];   // rows +2,3
    float4 wC = *(const float4*)&Wm2[l8 * 16 + 8];   // rows +4,5
    float4 wD = *(const float4*)&Wm2[l8 * 16 + 12];  // rows +6,7
    float4 bbA = *(const float4*)&bm1[l8 * 8];
    float4 bbB = *(const float4*)&bm1[l8 * 8 + 4];
    float ob0 = bm2[0], ob1 = bm2[1];

#pragma unroll
    for (int it = 0; it < 4; ++it) {
        int e = base + it * 32;
        int s = ei[e];
        int d = ei[E + e];
        int4 ua = *(const int4*)&Pa[(size_t)s * 64 + l8 * 8];
        int4 ub = *(const int4*)&Pb[(size_t)d * 64 + l8 * 8];
        float h0 = fmaxf(lobf(ua.x) + lobf(ub.x) + bbA.x, 0.f);
        float h1 = fmaxf(hibf(ua.x) + hibf(ub.x) + bbA.y, 0.f);
        float h2 = fmaxf(lobf(ua.y) + lobf(ub.y) + bbA.z, 0.f);
        float h3 = fmaxf(hibf(ua.y) + hibf(ub.y) + bbA.w, 0.f);
        float h4 = fmaxf(lobf(ua.z) + lobf(ub.z) + bbB.x, 0.f);
        float h5 = fmaxf(hibf(ua.z) + hibf(ub.z) + bbB.y, 0.f);
        float h6 = fmaxf(lobf(ua.w) + lobf(ub.w) + bbB.z, 0.f);
        float h7 = fmaxf(hibf(ua.w) + hibf(ub.w) + bbB.w, 0.f);
        float s0 = h0 * wA.x + h1 * wA.z + h2 * wB.x + h3 * wB.z
                 + h4 * wC.x + h5 * wC.z + h6 * wD.x + h7 * wD.z;
        float s1 = h0 * wA.y + h1 * wA.w + h2 * wB.y + h3 * wB.w
                 + h4 * wC.y + h5 * wC.w + h6 * wD.y + h7 * wD.w;
#pragma unroll
        for (int off = 4; off >= 1; off >>= 1) {
            s0 += __shfl_xor(s0, off, 64);
            s1 += __shfl_xor(s1, off, 64);
        }
        if (l8 == 0) {
            *(float2*)&out[(size_t)e * 2] = make_float2(s0 + ob0, s1 + ob1);
        }
    }
}

// ---------------- launch ----------------

extern "C" void kernel_launch(void* const* d_in, const int* in_sizes, int n_in,
                              void* d_out, int out_size, void* d_ws, size_t ws_size,
                              hipStream_t stream) {
    const float* x   = (const float*)d_in[0];
    const int*   ei  = (const int*)d_in[1];
    const float* W1l = (const float*)d_in[2];
    const float* b1l = (const float*)d_in[3];
    const float* W1r = (const float*)d_in[4];
    const float* W2l = (const float*)d_in[5];
    const float* b2l = (const float*)d_in[6];
    const float* W2r = (const float*)d_in[7];
    const float* Wm1 = (const float*)d_in[8];
    const float* bm1 = (const float*)d_in[9];
    const float* Wm2 = (const float*)d_in[10];
    const float* bm2 = (const float*)d_in[11];
    float* out = (float*)d_out;

    const int N = N_NODES, E = N_EDGES;

    // slots (all tables bf16):
    //   B0h: xl (gemm1) -> Pa (fused2)
    //   B1h: p1r (gemm1) -> p2r (fused1, same rows) [residual]
    //   B2 : bpk (CSR build, 3.2MB; dead after fused sort)
    //   B3h: Pb (fused2)
    //   B4h: p2l (fused1)  [fresh slot -- no alias with bpk]
    float* B0 = (float*)d_ws;
    float* B1 = B0 + (size_t)N * 64;
    float* B2 = B1 + (size_t)N * 64;
    unsigned short* B3h = (unsigned short*)(B2 + (size_t)N * 64);   // [N*64] 6.4MB
    unsigned short* B4h = B3h + (size_t)N * 64;                     // [N*64] 6.4MB
    int* rowptr   = (int*)(B4h + (size_t)N * 64);    // [N+1]
    int* elist    = rowptr + N + 1;                  // [E] 3.2 MB
    int* bofs     = elist + E;                       // [NBUK+1]
    int* gcur_pad = bofs + NBUK + 1;                 // [NBUK*PAD] 50KB
    int* bhist    = gcur_pad + NBUK * PAD;           // [NSB*NBUK] 613KB
    unsigned short* wt1 = (unsigned short*)(bhist + NSB * NBUK);  // [128*128] 32KB
    unsigned short* wt2 = wt1 + 128 * 128;                        // [128*64] 16KB
    unsigned short* wtm = wt2 + 128 * 64;                         // [128*64] 16KB
    unsigned int* bpk = (unsigned int*)B2;           // [E] 3.2 MB

    unsigned short* B0h = (unsigned short*)B0;
    unsigned short* B1h = (unsigned short*)B1;

    // CSR build (+fused weight prep): count -> scan
    count_prep_kernel<<<NSB + PREPB, 256, 0, stream>>>(
        ei, bhist, W1l, W1r, W2l, W2r, Wm1, wt1, wt2, wtm, E);
    scan_bcnt_kernel<<<1, 1024, 0, stream>>>(bhist, bofs, gcur_pad);

    // bucket scatter || conv1 GEMM: xl = x@W1l (B0h), p1r = x@W1r (B1h)
    scatter_gemm1_kernel<<<NSB + (N + 63) / 64, 256, 0, stream>>>(
        ei, gcur_pad, bpk, x, wt1, B0h, B1h, N, E);

    // fused sort + agg1 + conv2 GEMM: sort bucket -> rowptr/elist;
    //   h1 = relu(mean xl[src] + b1l + p1r) -> LDS;
    //   p2l = h1@W2l (B4h), p2r = h1@W2r (B1h, same rows as p1r)
    sort_agg_gemm_kernel<<<NBUK, 256, 0, stream>>>(
        bpk, bofs, rowptr, elist, B0h, B1h, b1l, wt2, B4h, B1h, N);

    // fused agg2 + edge-MLP GEMM: h2 = relu(mean p2l[src] + b2l + p2r) -> LDS;
    //   Pa = h2@Wm1_top (B0h), Pb = h2@Wm1_bot (B3h)
    agg_gemm_kernel<<<(N + 63) / 64, 256, 0, stream>>>(
        B4h, B1h, b2l, rowptr, elist, wtm, B0h, B3h, N);

    // per-edge: out = relu(Pa[src] + Pb[dst] + bm1) @ Wm2 + bm2
    edge_out_kernel<<<E / 128, 256, 0, stream>>>(B0h, B3h, ei, bm1, Wm2, bm2, out, E);
}